// Round 1
// baseline (89.618 us; speedup 1.0000x reference)
//
#include <hip/hip_runtime.h>
#include <hip/hip_fp16.h>

#define TLEN 512
#define KLEN 11
#define XPAD 256          // covers slot >= 1 for pad <= 255
#define XTOT 1024         // 16 KiB LDS: 1024 slots x 8 fp16 (8 batches interleaved)
#define NEGINF2 0xFC00FC00u

__device__ __forceinline__ unsigned pkmax_u(unsigned a, unsigned b) {
    unsigned d;
    asm("v_pk_max_f16 %0, %1, %2" : "=v"(d) : "v"(a), "v"(b));
    return d;
}
__device__ __forceinline__ unsigned pkadd_u(unsigned a, unsigned b) {
    unsigned d;
    asm("v_pk_add_f16 %0, %1, %2" : "=v"(d) : "v"(a), "v"(b));
    return d;
}

__device__ __forceinline__ unsigned wred_pkmax(unsigned x) {
    unsigned t;
    t = __builtin_amdgcn_update_dpp((int)NEGINF2, (int)x, 0x111, 0xF, 0xF, false);
    x = pkmax_u(x, t);
    t = __builtin_amdgcn_update_dpp((int)NEGINF2, (int)x, 0x112, 0xF, 0xF, false);
    x = pkmax_u(x, t);
    t = __builtin_amdgcn_update_dpp((int)NEGINF2, (int)x, 0x114, 0xF, 0xF, false);
    x = pkmax_u(x, t);
    t = __builtin_amdgcn_update_dpp((int)NEGINF2, (int)x, 0x118, 0xF, 0xF, false);
    x = pkmax_u(x, t);
    t = __builtin_amdgcn_update_dpp((int)NEGINF2, (int)x, 0x142, 0xA, 0xF, false);
    x = pkmax_u(x, t);
    t = __builtin_amdgcn_update_dpp((int)NEGINF2, (int)x, 0x143, 0xC, 0xF, false);
    x = pkmax_u(x, t);
    return (unsigned)__builtin_amdgcn_readlane((int)x, 63);
}
__device__ __forceinline__ unsigned wred_pkadd(unsigned x) {
    unsigned t;
    t = __builtin_amdgcn_update_dpp(0, (int)x, 0x111, 0xF, 0xF, false);
    x = pkadd_u(x, t);
    t = __builtin_amdgcn_update_dpp(0, (int)x, 0x112, 0xF, 0xF, false);
    x = pkadd_u(x, t);
    t = __builtin_amdgcn_update_dpp(0, (int)x, 0x114, 0xF, 0xF, false);
    x = pkadd_u(x, t);
    t = __builtin_amdgcn_update_dpp(0, (int)x, 0x118, 0xF, 0xF, false);
    x = pkadd_u(x, t);
    t = __builtin_amdgcn_update_dpp(0, (int)x, 0x142, 0xA, 0xF, false);
    x = pkadd_u(x, t);
    t = __builtin_amdgcn_update_dpp(0, (int)x, 0x143, 0xC, 0xF, false);
    x = pkadd_u(x, t);
    return (unsigned)__builtin_amdgcn_readlane((int)x, 63);
}

__device__ __forceinline__ __half2 as_h2(unsigned u) {
    __half2 h; __builtin_memcpy(&h, &u, 4); return h;
}
__device__ __forceinline__ unsigned as_u(__half2 h) {
    unsigned u; __builtin_memcpy(&u, &h, 4); return u;
}

// Single fused kernel: stage x (8-batch-interleaved fp16, zero-padded) into LDS
// directly from global (no d_ws round-trip, no second launch), then the
// taps-outer / chunks-inner conv + max/ppv reduction.
__global__ __launch_bounds__(256, 4) void rf_kernel_h4(
    const float* __restrict__ x, const float* __restrict__ weight,
    const float* __restrict__ bias, const int* __restrict__ dilation,
    const int* __restrict__ padding, const int* __restrict__ out_len,
    float* __restrict__ out, int K)
{
    __shared__ uint4 xs[XTOT];
    const int t = threadIdx.x;

    // ---- fused staging ----
    {
        const float* xg = x + (size_t)blockIdx.y * 8 * TLEN;
        const uint4 z = make_uint4(0u, 0u, 0u, 0u);
        xs[t]       = z;          // slots 0..255   (left pad)
        xs[768 + t] = z;          // slots 768..1023 (right pad)
        #pragma unroll
        for (int h = 0; h < 2; ++h) {
            const int pos = h * 256 + t;
            unsigned hv[8];
            #pragma unroll
            for (int q = 0; q < 8; ++q)
                hv[q] = (unsigned)__half_as_ushort(__float2half(xg[q * TLEN + pos]));
            uint4 v;
            v.x = hv[0] | (hv[1] << 16);
            v.y = hv[2] | (hv[3] << 16);
            v.z = hv[4] | (hv[5] << 16);
            v.w = hv[6] | (hv[7] << 16);
            xs[XPAD + pos] = v;   // lane-consecutive b128 writes: conflict-free
        }
    }
    __syncthreads();

    const int lane = t & 63;
    const int ks = __builtin_amdgcn_readfirstlane(blockIdx.x * 4 + (t >> 6));

    const int dil  = dilation[ks];
    const int pd   = padding[ks];
    const int olen = out_len[ks];
    float wjf[KLEN];
    __half2 w2[KLEN];
    #pragma unroll
    for (int j = 0; j < KLEN; ++j) {
        wjf[j] = weight[ks * KLEN + j];
        w2[j] = __float2half2_rn(wjf[j]);
    }
    const __half2 bias2 = __float2half2_rn(bias[ks]);
    const __half2 zero2 = __float2half2_rn(0.0f);

    const int vbase = XPAD + lane - pd;

    __half2 acc[8][4];
    #pragma unroll
    for (int c = 0; c < 8; ++c)
        #pragma unroll
        for (int q = 0; q < 4; ++q) acc[c][q] = bias2;

    #pragma unroll
    for (int j = 0; j < KLEN; ++j) {
        if (wjf[j] != 0.0f) {                          // uniform: skip zero taps
            const uint4* xp = xs + (vbase + j * dil);  // one addr per tap
            #pragma unroll
            for (int c = 0; c < 8; ++c) {
                if (c * 64 < olen) {                   // uniform: skip dead chunks
                    const uint4 r = xp[c * 64];        // ds_read_b128, imm c*1024
                    acc[c][0] = __hfma2(w2[j], as_h2(r.x), acc[c][0]);
                    acc[c][1] = __hfma2(w2[j], as_h2(r.y), acc[c][1]);
                    acc[c][2] = __hfma2(w2[j], as_h2(r.z), acc[c][2]);
                    acc[c][3] = __hfma2(w2[j], as_h2(r.w), acc[c][3]);
                }
            }
        }
    }

    unsigned mxu[4], cfu[4];
    #pragma unroll
    for (int q = 0; q < 4; ++q) { mxu[q] = NEGINF2; cfu[q] = 0u; }

    #pragma unroll
    for (int c = 0; c < 8; ++c) {
        const int p0 = c * 64;
        if (p0 + 64 <= olen) {                         // fully-valid chunk
            #pragma unroll
            for (int q = 0; q < 4; ++q) {
                mxu[q] = pkmax_u(mxu[q], as_u(acc[c][q]));
                cfu[q] = pkadd_u(cfu[q], as_u(__hgt2(acc[c][q], zero2)));
            }
        } else if (p0 < olen) {                        // boundary chunk
            const bool vld = lane < (olen - p0);
            #pragma unroll
            for (int q = 0; q < 4; ++q) {
                const unsigned a = vld ? as_u(acc[c][q]) : NEGINF2;
                mxu[q] = pkmax_u(mxu[q], a);
                const unsigned g = vld ? as_u(__hgt2(acc[c][q], zero2)) : 0u;
                cfu[q] = pkadd_u(cfu[q], g);
            }
        }
    }

    #pragma unroll
    for (int q = 0; q < 4; ++q) {
        mxu[q] = wred_pkmax(mxu[q]);
        cfu[q] = wred_pkadd(cfu[q]);
    }

    if (lane == 0) {
        const float inv = 1.0f / (float)olen;
        const size_t row = (size_t)2 * K;
        float* o = out + (size_t)blockIdx.y * 8 * row + 2 * ks;
        #pragma unroll
        for (int q = 0; q < 4; ++q) {
            const __half2 m = as_h2(mxu[q]);
            const __half2 c = as_h2(cfu[q]);
            *(float2*)(o + (2 * q) * row)     = make_float2(__low2float(m),  __low2float(c) * inv);
            *(float2*)(o + (2 * q + 1) * row) = make_float2(__high2float(m), __high2float(c) * inv);
        }
    }
}

extern "C" void kernel_launch(void* const* d_in, const int* in_sizes, int n_in,
                              void* d_out, int out_size, void* d_ws, size_t ws_size,
                              hipStream_t stream) {
    const float* x    = (const float*)d_in[0];
    const float* w    = (const float*)d_in[1];
    const float* bias = (const float*)d_in[2];
    const int* dil    = (const int*)d_in[3];
    const int* pad    = (const int*)d_in[4];
    const int* olen   = (const int*)d_in[5];
    float* out        = (float*)d_out;

    const int K = in_sizes[2];          // 4096
    const int B = in_sizes[0] / TLEN;   // 32
    const int G = B / 8;                // 4 batch groups

    dim3 grid(K / 4, G);                // 1024 x 4 blocks, 4 waves each
    rf_kernel_h4<<<grid, 256, 0, stream>>>(x, w, bias, dil, pad, olen, out, K);
    (void)n_in; (void)out_size; (void)d_ws; (void)ws_size;
}